// Round 17
// baseline (934.488 us; speedup 1.0000x reference)
//
#include <hip/hip_runtime.h>
#include <stdint.h>

#define B_SZ   4096
#define IN_SZ  1024
#define NE     8
#define NC     1000
#define HIDE   16384   // HID*E
#define OUTE   1024    // OUT per expert
#define GEPS   1e-6f
#define NSPLIT 2
#define KSPL   8192    // HIDE / NSPLIT

// W2 conversion spans (elements), distributed over the gating chain
#define SA     33554432
#define SB     41943040
#define SC     25165824
#define SD     12582912
#define SE     20971520

typedef __attribute__((ext_vector_type(8))) short short8;
typedef __attribute__((ext_vector_type(4))) float floatx4;

__device__ __forceinline__ unsigned short f2bf(float f) {
    unsigned u = __float_as_uint(f);
    u += 0x7fffu + ((u >> 16) & 1u);
    return (unsigned short)(u >> 16);
}
__device__ __forceinline__ float bf2f(unsigned short h) {
    return __uint_as_float(((unsigned)h) << 16);
}

__device__ __forceinline__ void async16(const void* g, void* l) {
    __builtin_amdgcn_global_load_lds(
        (const __attribute__((address_space(1))) void*)g,
        (__attribute__((address_space(3))) void*)l, 16, 0, 0);
}

__device__ __forceinline__ void cvt_span(const float* __restrict__ src,
                                         unsigned short* __restrict__ dst,
                                         int n, int bid, int nb) {
    const int bdim = (int)blockDim.x;
    int i = (bid * bdim + (int)threadIdx.x) * 8;
    int stride = nb * bdim * 8;
    for (; i < n; i += stride) {
        float4 v0 = *(const float4*)(src + i);
        float4 v1 = *(const float4*)(src + i + 4);
        uint4 w;
        w.x = (unsigned)f2bf(v0.x) | ((unsigned)f2bf(v0.y) << 16);
        w.y = (unsigned)f2bf(v0.z) | ((unsigned)f2bf(v0.w) << 16);
        w.z = (unsigned)f2bf(v1.x) | ((unsigned)f2bf(v1.y) << 16);
        w.w = (unsigned)f2bf(v1.z) | ((unsigned)f2bf(v1.w) << 16);
        *(uint4*)(dst + i) = w;
    }
}

// ---- gating (fp32 exact) + bf16 x + W1/Wc cvt + W2 span A ---------------------
__global__ __launch_bounds__(256) void k_gatef(const float* __restrict__ x,
                                               const float* __restrict__ Wg,
                                               const float* __restrict__ bg,
                                               float* __restrict__ logits,
                                               float* __restrict__ Gx,
                                               unsigned short* __restrict__ xb,
                                               const float* __restrict__ W1,
                                               unsigned short* __restrict__ w1b,
                                               const float* __restrict__ Wc,
                                               unsigned short* __restrict__ wcb,
                                               const float* __restrict__ W2,
                                               unsigned short* __restrict__ w2b) {
    const int bid = blockIdx.x;
    if (bid >= 1024) {
        if (bid < 1536)      cvt_span(W1, w1b, HIDE * IN_SZ, bid - 1024, 512);
        else if (bid < 1600) cvt_span(Wc, wcb, NC * IN_SZ,   bid - 1536, 64);
        else                 cvt_span(W2, w2b, SA,           bid - 1600, 1024);
        return;
    }
    int wid = threadIdx.x >> 6, lane = threadIdx.x & 63;
    int b = bid * 4 + wid;
    const float* xr = x + (size_t)b * IN_SZ;
    float xv[16];
#pragma unroll
    for (int t = 0; t < 16; ++t) xv[t] = xr[lane + 64 * t];
    unsigned short* xbr = xb + (size_t)b * IN_SZ;
#pragma unroll
    for (int t = 0; t < 16; ++t) xbr[lane + 64 * t] = f2bf(xv[t]);
    float lg[NE];
#pragma unroll
    for (int e = 0; e < NE; ++e) {
        const float* wr = Wg + e * IN_SZ;
        float s = 0.f;
#pragma unroll
        for (int t = 0; t < 16; ++t) s += xv[t] * wr[lane + 64 * t];
#pragma unroll
        for (int m = 32; m >= 1; m >>= 1) s += __shfl_xor(s, m, 64);
        lg[e] = s + bg[e];
    }
    if (lane == 0) {
        float ss = 0.f;
#pragma unroll
        for (int e = 0; e < NE; ++e) { logits[b * NE + e] = lg[e]; ss += lg[e] * lg[e]; }
        Gx[b] = sqrtf(ss);
    }
}

__global__ __launch_bounds__(1024) void k_gsumf(const float* __restrict__ Gx,
                                                float* __restrict__ gsum, int* __restrict__ ctrl,
                                                const float* __restrict__ W2,
                                                unsigned short* __restrict__ w2b) {
    if (blockIdx.x > 0) {
        cvt_span(W2 + SA, w2b + SA, SB, blockIdx.x - 1, 2047);
        return;
    }
    __shared__ float sm[1024];
    int t = threadIdx.x;
    if (t < 24) ctrl[t] = 0;
    sm[t] = Gx[t] + Gx[t + 1024] + Gx[t + 2048] + Gx[t + 3072];
    __syncthreads();
    for (int m = 512; m >= 1; m >>= 1) {
        if (t < m) sm[t] += sm[t + m];
        __syncthreads();
    }
    if (t == 0) gsum[0] = sm[0];
}

__global__ __launch_bounds__(256) void k_topkf(const float* __restrict__ logits,
                                               const float* __restrict__ Gx,
                                               const float* __restrict__ gsum,
                                               const float* __restrict__ gamma,
                                               const float* __restrict__ beta,
                                               int* __restrict__ tidx, float* __restrict__ tp,
                                               int* __restrict__ counts,
                                               const float* __restrict__ W2,
                                               unsigned short* __restrict__ w2b) {
    if (blockIdx.x >= 16) {
        cvt_span(W2 + (SA + SB), w2b + (SA + SB), SC, blockIdx.x - 16, 1024);
        return;
    }
    int b = blockIdx.x * 256 + threadIdx.x;
    float nx = Gx[b] / (gsum[0] * (1.0f / (float)B_SZ) + GEPS);
    float l[NE];
    float mx = -1e30f;
#pragma unroll
    for (int e = 0; e < NE; ++e) {
        l[e] = gamma[e] * (logits[b * NE + e] * nx) + beta[e];
        mx = fmaxf(mx, l[e]);
    }
    float se = 0.f;
#pragma unroll
    for (int e = 0; e < NE; ++e) { l[e] = expf(l[e] - mx); se += l[e]; }
    float inv = 1.f / se;
    int i0 = 0; float p0 = l[0];
#pragma unroll
    for (int e = 1; e < NE; ++e) if (l[e] > p0) { p0 = l[e]; i0 = e; }
    int i1 = -1; float p1 = -1.f;
#pragma unroll
    for (int e = 0; e < NE; ++e) if (e != i0 && l[e] > p1) { p1 = l[e]; i1 = e; }
    tidx[b * 2 + 0] = i0; tidx[b * 2 + 1] = i1;
    tp[b * 2 + 0] = p0 * inv; tp[b * 2 + 1] = p1 * inv;
    atomicAdd(&counts[i0], 1);
    atomicAdd(&counts[i1], 1);
}

__global__ __launch_bounds__(256) void k_offsetsf(const int* __restrict__ counts,
                                                  int* __restrict__ offs,
                                                  const float* __restrict__ W2,
                                                  unsigned short* __restrict__ w2b) {
    if (blockIdx.x > 0) {
        cvt_span(W2 + (SA + SB + SC), w2b + (SA + SB + SC), SD, blockIdx.x - 1, 511);
        return;
    }
    if (threadIdx.x == 0) {
        int a = 0;
        for (int e = 0; e < NE; ++e) { offs[e] = a; a += counts[e]; }
    }
}

__global__ __launch_bounds__(256) void k_fillf(const int* __restrict__ tidx, const float* __restrict__ tp,
                                               const int* __restrict__ offs, int* __restrict__ cursors,
                                               int* __restrict__ rowsw, int* __restrict__ slotof,
                                               const float* __restrict__ W2,
                                               unsigned short* __restrict__ w2b) {
    if (blockIdx.x >= 16) {
        cvt_span(W2 + (SA + SB + SC + SD), w2b + (SA + SB + SC + SD), SE, blockIdx.x - 16, 1008);
        return;
    }
    int b = blockIdx.x * 256 + threadIdx.x;
#pragma unroll
    for (int k = 0; k < 2; ++k) {
        int e = tidx[b * 2 + k];
        int pos = atomicAdd(&cursors[e], 1);
        int at = offs[e] + pos;
        rowsw[at] = b * 2 + k;
        slotof[b * 2 + k] = at;
    }
}

// ====== NEW: 128x128 / BK=32 core, 32KB LDS dbuf -> 4 resident blocks/CU =======
// Per buffer (16KB): A 128x32 (8KB) | B 128x32 (8KB). 64B rows = 4x16B slots.
// LDS[r][slot] holds global chunk slot^((r>>1)&3) (r14-verified 0-conflict).
// Read slot = (lane>>4)^((lane>>1)&3); stage src chunk = (t&3)^((t>>3)&3).
// Loop discipline identical to r6: stage(buf^1,t+1) -> compute(buf) -> sync.

__device__ __forceinline__ void stage32(const unsigned short* const* pa,
                                        const unsigned short* const* pb,
                                        char* bufc, int koff, int tid) {
#pragma unroll
    for (int c = 0; c < 2; ++c)
        async16(pa[c] + koff, bufc + c * 4096 + tid * 16);
#pragma unroll
    for (int c = 0; c < 2; ++c)
        async16(pb[c] + koff, bufc + 8192 + c * 4096 + tid * 16);
}

__device__ __forceinline__ void compute32(const short* buf, const int* aoff, const int* boff,
                                          floatx4 acc[4][4]) {
    const short* sA = buf;
    const short* sB = buf + 4096;
    short8 av[4], bv[4];
#pragma unroll
    for (int i = 0; i < 4; ++i) {
        av[i] = *(const short8*)(sA + aoff[i]);
        bv[i] = *(const short8*)(sB + boff[i]);
    }
    asm volatile("s_waitcnt lgkmcnt(0)" ::: "memory");
    __builtin_amdgcn_sched_barrier(0);
    __builtin_amdgcn_s_setprio(1);
#pragma unroll
    for (int i = 0; i < 4; ++i)
#pragma unroll
        for (int j = 0; j < 4; ++j)
            acc[i][j] = __builtin_amdgcn_mfma_f32_16x16x32_bf16(av[i], bv[j], acc[i][j], 0, 0, 0);
    __builtin_amdgcn_s_setprio(0);
}

// nkt (K/32) must be even. smem = 32768B dynamic.
__device__ __forceinline__ void core32db(const unsigned short* const* pa,
                                         const unsigned short* const* pb,
                                         short* smem, int nkt, int wm, int wn,
                                         int tid, int lane, floatx4 acc[4][4]) {
    char* b0c = (char*)smem;
    char* b1c = b0c + 16384;
    const int soff = ((lane >> 4) ^ ((lane >> 1) & 3)) * 8;
    int aoff[4], boff[4];
#pragma unroll
    for (int i = 0; i < 4; ++i) {
        aoff[i] = (wm * 64 + i * 16 + (lane & 15)) * 32 + soff;
        boff[i] = (wn * 64 + i * 16 + (lane & 15)) * 32 + soff;
    }
    stage32(pa, pb, b0c, 0, tid);
    __syncthreads();
#pragma unroll 1
    for (int kt = 0; kt < nkt; kt += 2) {
        if (kt + 1 < nkt) stage32(pa, pb, b1c, (kt + 1) * 32, tid);
        compute32(smem, aoff, boff, acc);
        __syncthreads();
        if (kt + 2 < nkt) stage32(pa, pb, b0c, (kt + 2) * 32, tid);
        compute32(smem + 8192, aoff, boff, acc);
        __syncthreads();
    }
}

// GEMM1: h = relu(x @ W1^T + b1)  — 128x128 tiles, grid 4096, BK=32 core
__global__ __launch_bounds__(256) void k_h8(const unsigned short* __restrict__ xb,
                                            const unsigned short* __restrict__ w1b,
                                            const float* __restrict__ b1,
                                            unsigned short* __restrict__ hout) {
    extern __shared__ short smem[];
    const int tid = threadIdx.x, lane = tid & 63, wid = tid >> 6;
    const int wm = wid >> 1, wn = wid & 1;
    const int wg = (blockIdx.x & 7) * (gridDim.x >> 3) + (blockIdx.x >> 3);
    const int mt = wg & 31, nt = wg >> 5;
    const int m0 = mt * 128, n0 = nt * 128;
    const int sr4 = tid >> 2;                        // 0..63
    const int chk = ((tid & 3) ^ ((tid >> 3) & 3)) * 8;
    const unsigned short* pa[2];
    const unsigned short* pb[2];
#pragma unroll
    for (int c = 0; c < 2; ++c) {
        pa[c] = xb  + (size_t)(m0 + 64 * c + sr4) * IN_SZ + chk;
        pb[c] = w1b + (size_t)(n0 + 64 * c + sr4) * IN_SZ + chk;
    }
    floatx4 acc[4][4] = {};
    core32db(pa, pb, smem, IN_SZ / 32, wm, wn, tid, lane, acc);
#pragma unroll
    for (int i = 0; i < 4; ++i)
#pragma unroll
        for (int j = 0; j < 4; ++j)
#pragma unroll
            for (int r = 0; r < 4; ++r) {
                int row = m0 + wm * 64 + i * 16 + (lane >> 4) * 4 + r;
                int col = n0 + wn * 64 + j * 16 + (lane & 15);
                float v = acc[i][j][r] + b1[col];
                hout[(size_t)row * HIDE + col] = f2bf(fmaxf(v, 0.f));
            }
}

// GEMM2 grouped, split-K=2, BK=32 core: gathered h rows x W2 expert slice
__global__ __launch_bounds__(256) void k_moe(const unsigned short* __restrict__ h,
                                             const unsigned short* __restrict__ w2b,
                                             const int* __restrict__ counts,
                                             const int* __restrict__ offs,
                                             const int* __restrict__ rowsw,
                                             unsigned short* __restrict__ parts) {
    // grid 4096 = 8e x 2sp x 8nt x 32mt; mt innermost -> same-XCD share B-panel
    const int wg = (blockIdx.x & 7) * (gridDim.x >> 3) + (blockIdx.x >> 3);
    const int mt = wg & 31, nt = (wg >> 5) & 7, sp = (wg >> 8) & 1, e = wg >> 9;
    const int gn = counts[e];
    if (mt * 128 >= gn) return;
    const int gbase = offs[e];
    extern __shared__ short smem[];
    const int tid = threadIdx.x, lane = tid & 63, wid = tid >> 6;
    const int wm = wid >> 1, wn = wid & 1;
    const int sr4 = tid >> 2;
    const int chk = ((tid & 3) ^ ((tid >> 3) & 3)) * 8;
    const unsigned short* pa[2];
    const unsigned short* pb[2];
#pragma unroll
    for (int c = 0; c < 2; ++c) {
        int lr = mt * 128 + 64 * c + sr4;
        if (lr > gn - 1) lr = gn - 1;
        int grow = rowsw[gbase + lr] >> 1;
        pa[c] = h + (size_t)grow * HIDE + sp * KSPL + chk;
        pb[c] = w2b + (size_t)(e * OUTE + nt * 128 + 64 * c + sr4) * HIDE + sp * KSPL + chk;
    }
    floatx4 acc[4][4] = {};
    core32db(pa, pb, smem, KSPL / 32, wm, wn, tid, lane, acc);
    unsigned short* pbase = parts + (size_t)sp * B_SZ * 2 * OUTE;
#pragma unroll
    for (int i = 0; i < 4; ++i)
#pragma unroll
        for (int j = 0; j < 4; ++j)
#pragma unroll
            for (int r = 0; r < 4; ++r) {
                int lr = mt * 128 + wm * 64 + i * 16 + (lane >> 4) * 4 + r;
                if (lr < gn) {
                    int at = gbase + lr;
                    int col = nt * 128 + wn * 64 + j * 16 + (lane & 15);
                    pbase[(size_t)at * OUTE + col] = f2bf(acc[i][j][r]);
                }
            }
}

// reduce: ymix[b] = sum_k tp[b,k] * (sum_sp parts[sp][slot(b,k)] + b2[e_k])
__global__ __launch_bounds__(256) void k_reduce(const unsigned short* __restrict__ parts,
                                                const int* __restrict__ slotof,
                                                const int* __restrict__ tidx,
                                                const float* __restrict__ tp,
                                                const float* __restrict__ b2,
                                                unsigned short* __restrict__ ymix) {
    int i = blockIdx.x * 256 + threadIdx.x;
    int b = i >> 8, col = (i & 255) * 4;
    int at0 = slotof[b * 2], at1 = slotof[b * 2 + 1];
    int e0 = tidx[b * 2], e1 = tidx[b * 2 + 1];
    float q0 = tp[b * 2], q1 = tp[b * 2 + 1];
    float y0[4] = {0.f, 0.f, 0.f, 0.f}, y1[4] = {0.f, 0.f, 0.f, 0.f};
#pragma unroll
    for (int sp = 0; sp < NSPLIT; ++sp) {
        ushort4 u0 = *(const ushort4*)(parts + ((size_t)sp * B_SZ * 2 + at0) * OUTE + col);
        ushort4 u1 = *(const ushort4*)(parts + ((size_t)sp * B_SZ * 2 + at1) * OUTE + col);
        y0[0] += bf2f(u0.x); y0[1] += bf2f(u0.y); y0[2] += bf2f(u0.z); y0[3] += bf2f(u0.w);
        y1[0] += bf2f(u1.x); y1[1] += bf2f(u1.y); y1[2] += bf2f(u1.z); y1[3] += bf2f(u1.w);
    }
    float4 bb0 = *(const float4*)(b2 + (size_t)e0 * OUTE + col);
    float4 bb1 = *(const float4*)(b2 + (size_t)e1 * OUTE + col);
    ushort4 o;
    o.x = f2bf(q0 * (y0[0] + bb0.x) + q1 * (y1[0] + bb1.x));
    o.y = f2bf(q0 * (y0[1] + bb0.y) + q1 * (y1[1] + bb1.y));
    o.z = f2bf(q0 * (y0[2] + bb0.z) + q1 * (y1[2] + bb1.z));
    o.w = f2bf(q0 * (y0[3] + bb0.w) + q1 * (y1[3] + bb1.w));
    *(ushort4*)(ymix + (size_t)b * OUTE + col) = o;
}

// ---- 128x128 / BK=64 core retained for the small final GEMM (r6-proven) -------
__device__ __forceinline__ void compute_bk64(const short* buf, const int* aoff, const int* boff,
                                             floatx4 acc[4][4]) {
    const short* sA = buf;
    const short* sB = buf + 8192;
    short8 a0[4], a1[4], b0[4], b1[4];
#pragma unroll
    for (int i = 0; i < 4; ++i) {
        a0[i] = *(const short8*)(sA + aoff[i]);
        a1[i] = *(const short8*)(sA + (aoff[i] ^ 32));
        b0[i] = *(const short8*)(sB + boff[i]);
        b1[i] = *(const short8*)(sB + (boff[i] ^ 32));
    }
    asm volatile("s_waitcnt lgkmcnt(0)" ::: "memory");
    __builtin_amdgcn_sched_barrier(0);
    __builtin_amdgcn_s_setprio(1);
#pragma unroll
    for (int i = 0; i < 4; ++i)
#pragma unroll
        for (int j = 0; j < 4; ++j) {
            acc[i][j] = __builtin_amdgcn_mfma_f32_16x16x32_bf16(a0[i], b0[j], acc[i][j], 0, 0, 0);
            acc[i][j] = __builtin_amdgcn_mfma_f32_16x16x32_bf16(a1[i], b1[j], acc[i][j], 0, 0, 0);
        }
    __builtin_amdgcn_s_setprio(0);
}

__device__ __forceinline__ void stage_bk64(const unsigned short* const* pa,
                                           const unsigned short* const* pb,
                                           char* bufc, int koff, int tid) {
#pragma unroll
    for (int c = 0; c < 4; ++c) {
        async16(pa[c] + koff, bufc + c * 4096 + tid * 16);
        async16(pb[c] + koff, bufc + 16384 + c * 4096 + tid * 16);
    }
}

__device__ __forceinline__ void core64db(const unsigned short* const* pa,
                                         const unsigned short* const* pb,
                                         short* smem, int nkt, int wm, int wn,
                                         int tid, int lane, floatx4 acc[4][4]) {
    char* b0c = (char*)smem;
    char* b1c = b0c + 32768;
    const int sl = ((lane >> 4) ^ (lane & 7)) * 8;
    int aoff[4], boff[4];
#pragma unroll
    for (int i = 0; i < 4; ++i) {
        aoff[i] = (wm * 64 + i * 16 + (lane & 15)) * 64 + sl;
        boff[i] = (wn * 64 + i * 16 + (lane & 15)) * 64 + sl;
    }
    stage_bk64(pa, pb, b0c, 0, tid);
    __syncthreads();
#pragma unroll 1
    for (int kt = 0; kt < nkt; kt += 2) {
        if (kt + 1 < nkt) stage_bk64(pa, pb, b1c, (kt + 1) * 64, tid);
        compute_bk64(smem, aoff, boff, acc);
        __syncthreads();
        if (kt + 2 < nkt) stage_bk64(pa, pb, b0c, (kt + 2) * 64, tid);
        compute_bk64(smem + 16384, aoff, boff, acc);
        __syncthreads();
    }
}

// GEMM3: out = ymix @ Wc^T + bc  (BK=64 core, B rows clamped to NC)
__global__ __launch_bounds__(256) void k_gemm_out(const unsigned short* __restrict__ ymix,
                                                  const unsigned short* __restrict__ wcb,
                                                  const float* __restrict__ bc,
                                                  float* __restrict__ out) {
    const int mt = blockIdx.x >> 3, nt = blockIdx.x & 7;
    const int m0 = mt * 128, n0 = nt * 128;
    extern __shared__ short smem[];
    const int tid = threadIdx.x, lane = tid & 63, wid = tid >> 6;
    const int wm = wid >> 1, wn = wid & 1;
    const int srow = tid >> 3;
    const int cswz = ((tid & 7) ^ (srow & 7)) * 8;
    const unsigned short* pa[4];
    const unsigned short* pb[4];
#pragma unroll
    for (int c = 0; c < 4; ++c) {
        pa[c] = ymix + (size_t)(m0 + 32 * c + srow) * IN_SZ + cswz;
        int br = n0 + 32 * c + srow; if (br > NC - 1) br = NC - 1;
        pb[c] = wcb + (size_t)br * IN_SZ + cswz;
    }
    floatx4 acc[4][4] = {};
    core64db(pa, pb, smem, IN_SZ / 64, wm, wn, tid, lane, acc);
#pragma unroll
    for (int i = 0; i < 4; ++i)
#pragma unroll
        for (int j = 0; j < 4; ++j)
#pragma unroll
            for (int r = 0; r < 4; ++r) {
                int row = m0 + wm * 64 + i * 16 + (lane >> 4) * 4 + r;
                int col = n0 + wn * 64 + j * 16 + (lane & 15);
                if (col < NC)
                    out[(size_t)row * NC + col] = acc[i][j][r] + bc[col];
            }
}

extern "C" void kernel_launch(void* const* d_in, const int* in_sizes, int n_in,
                              void* d_out, int out_size, void* d_ws, size_t ws_size,
                              hipStream_t stream) {
    const float* x     = (const float*)d_in[0];
    const float* Wg    = (const float*)d_in[1];
    const float* bg    = (const float*)d_in[2];
    const float* gamma = (const float*)d_in[3];
    const float* beta  = (const float*)d_in[4];
    const float* W1    = (const float*)d_in[5];
    const float* b1    = (const float*)d_in[6];
    const float* W2    = (const float*)d_in[7];
    const float* b2    = (const float*)d_in[8];
    const float* Wc    = (const float*)d_in[9];
    const float* bc    = (const float*)d_in[10];
    float* out = (float*)d_out;

    char* ws = (char*)d_ws;
    size_t o = 0;
    auto carve = [&](size_t bytes) { char* p = ws + o; o += (bytes + 255) & ~(size_t)255; return p; };
    unsigned short* xb    = (unsigned short*)carve((size_t)B_SZ * IN_SZ * 2);
    unsigned short* w1b   = (unsigned short*)carve((size_t)HIDE * IN_SZ * 2);
    unsigned short* w2b   = (unsigned short*)carve((size_t)NE * OUTE * HIDE * 2);
    unsigned short* wcb   = (unsigned short*)carve((size_t)NC * IN_SZ * 2);
    unsigned short* h     = (unsigned short*)carve((size_t)B_SZ * HIDE * 2);
    unsigned short* parts = (unsigned short*)carve((size_t)NSPLIT * B_SZ * 2 * OUTE * 2);
    unsigned short* ymix  = (unsigned short*)carve((size_t)B_SZ * OUTE * 2);
    float* logits = (float*)carve((size_t)B_SZ * NE * 4);
    float* Gx     = (float*)carve((size_t)B_SZ * 4);
    int*   tidx   = (int*)carve((size_t)B_SZ * 2 * 4);
    float* tp     = (float*)carve((size_t)B_SZ * 2 * 4);
    int*   rowsw  = (int*)carve((size_t)B_SZ * 2 * 4);
    int*   slotof = (int*)carve((size_t)B_SZ * 2 * 4);
    int*   ctrl   = (int*)carve(256);
    int* counts  = ctrl;
    int* cursors = ctrl + 8;
    int* offs    = ctrl + 16;
    float* gsum  = (float*)(ctrl + 24);

    // dynamic LDS caps (idempotent, not captured)
    hipFuncSetAttribute((const void*)k_h8,       hipFuncAttributeMaxDynamicSharedMemorySize, 32768);
    hipFuncSetAttribute((const void*)k_moe,      hipFuncAttributeMaxDynamicSharedMemorySize, 32768);
    hipFuncSetAttribute((const void*)k_gemm_out, hipFuncAttributeMaxDynamicSharedMemorySize, 65536);

    // gating chain carrying disjoint W2-conversion slices (r13/r16-identical)
    k_gatef<<<2624, 256, 0, stream>>>(x, Wg, bg, logits, Gx, xb, W1, w1b, Wc, wcb, W2, w2b);
    k_gsumf<<<2048, 1024, 0, stream>>>(Gx, gsum, ctrl, W2, w2b);
    k_topkf<<<1040, 256, 0, stream>>>(logits, Gx, gsum, gamma, beta, tidx, tp, counts, W2, w2b);
    k_offsetsf<<<512, 256, 0, stream>>>(counts, offs, W2, w2b);
    k_fillf<<<1024, 256, 0, stream>>>(tidx, tp, offs, cursors, rowsw, slotof, W2, w2b);

    // GEMMs: BK=32 cores (4 resident blocks/CU) for h8 + moe; BK=64 for out
    k_h8<<<(B_SZ / 128) * (HIDE / 128), 256, 32768, stream>>>(xb, w1b, b1, h);
    k_moe<<<NE * 32 * 8 * NSPLIT, 256, 32768, stream>>>(h, w2b, counts, offs, rowsw, parts);
    k_reduce<<<B_SZ, 256, 0, stream>>>(parts, slotof, tidx, tp, b2, ymix);
    k_gemm_out<<<(B_SZ / 128) * 8, 256, 65536, stream>>>(ymix, wcb, bc, out);
}

// Round 18
// 883.491 us; speedup vs baseline: 1.0577x; 1.0577x over previous
//
#include <hip/hip_runtime.h>
#include <stdint.h>

#define B_SZ   4096
#define IN_SZ  1024
#define NE     8
#define NC     1000
#define HIDE   16384   // HID*E
#define OUTE   1024    // OUT per expert
#define GEPS   1e-6f
#define NSPLIT 2
#define KSPL   8192    // HIDE / NSPLIT

// W2 conversion spans (elements), distributed over the gating chain
#define SA     33554432
#define SB     41943040
#define SC     25165824
#define SD     12582912
#define SE     20971520

typedef __attribute__((ext_vector_type(8))) short short8;
typedef __attribute__((ext_vector_type(4))) float floatx4;

__device__ __forceinline__ unsigned short f2bf(float f) {
    unsigned u = __float_as_uint(f);
    u += 0x7fffu + ((u >> 16) & 1u);
    return (unsigned short)(u >> 16);
}
__device__ __forceinline__ float bf2f(unsigned short h) {
    return __uint_as_float(((unsigned)h) << 16);
}

__device__ __forceinline__ void async16(const void* g, void* l) {
    __builtin_amdgcn_global_load_lds(
        (const __attribute__((address_space(1))) void*)g,
        (__attribute__((address_space(3))) void*)l, 16, 0, 0);
}

__device__ __forceinline__ void cvt_span(const float* __restrict__ src,
                                         unsigned short* __restrict__ dst,
                                         int n, int bid, int nb) {
    const int bdim = (int)blockDim.x;
    int i = (bid * bdim + (int)threadIdx.x) * 8;
    int stride = nb * bdim * 8;
    for (; i < n; i += stride) {
        float4 v0 = *(const float4*)(src + i);
        float4 v1 = *(const float4*)(src + i + 4);
        uint4 w;
        w.x = (unsigned)f2bf(v0.x) | ((unsigned)f2bf(v0.y) << 16);
        w.y = (unsigned)f2bf(v0.z) | ((unsigned)f2bf(v0.w) << 16);
        w.z = (unsigned)f2bf(v1.x) | ((unsigned)f2bf(v1.y) << 16);
        w.w = (unsigned)f2bf(v1.z) | ((unsigned)f2bf(v1.w) << 16);
        *(uint4*)(dst + i) = w;
    }
}

// ---- gating (fp32 exact) + bf16 x + W1/Wc cvt + W2 span A ---------------------
__global__ __launch_bounds__(256) void k_gatef(const float* __restrict__ x,
                                               const float* __restrict__ Wg,
                                               const float* __restrict__ bg,
                                               float* __restrict__ logits,
                                               float* __restrict__ Gx,
                                               unsigned short* __restrict__ xb,
                                               const float* __restrict__ W1,
                                               unsigned short* __restrict__ w1b,
                                               const float* __restrict__ Wc,
                                               unsigned short* __restrict__ wcb,
                                               const float* __restrict__ W2,
                                               unsigned short* __restrict__ w2b) {
    const int bid = blockIdx.x;
    if (bid >= 1024) {
        if (bid < 1536)      cvt_span(W1, w1b, HIDE * IN_SZ, bid - 1024, 512);
        else if (bid < 1600) cvt_span(Wc, wcb, NC * IN_SZ,   bid - 1536, 64);
        else                 cvt_span(W2, w2b, SA,           bid - 1600, 1024);
        return;
    }
    int wid = threadIdx.x >> 6, lane = threadIdx.x & 63;
    int b = bid * 4 + wid;
    const float* xr = x + (size_t)b * IN_SZ;
    float xv[16];
#pragma unroll
    for (int t = 0; t < 16; ++t) xv[t] = xr[lane + 64 * t];
    unsigned short* xbr = xb + (size_t)b * IN_SZ;
#pragma unroll
    for (int t = 0; t < 16; ++t) xbr[lane + 64 * t] = f2bf(xv[t]);
    float lg[NE];
#pragma unroll
    for (int e = 0; e < NE; ++e) {
        const float* wr = Wg + e * IN_SZ;
        float s = 0.f;
#pragma unroll
        for (int t = 0; t < 16; ++t) s += xv[t] * wr[lane + 64 * t];
#pragma unroll
        for (int m = 32; m >= 1; m >>= 1) s += __shfl_xor(s, m, 64);
        lg[e] = s + bg[e];
    }
    if (lane == 0) {
        float ss = 0.f;
#pragma unroll
        for (int e = 0; e < NE; ++e) { logits[b * NE + e] = lg[e]; ss += lg[e] * lg[e]; }
        Gx[b] = sqrtf(ss);
    }
}

__global__ __launch_bounds__(1024) void k_gsumf(const float* __restrict__ Gx,
                                                float* __restrict__ gsum, int* __restrict__ ctrl,
                                                const float* __restrict__ W2,
                                                unsigned short* __restrict__ w2b) {
    if (blockIdx.x > 0) {
        cvt_span(W2 + SA, w2b + SA, SB, blockIdx.x - 1, 2047);
        return;
    }
    __shared__ float sm[1024];
    int t = threadIdx.x;
    if (t < 24) ctrl[t] = 0;
    sm[t] = Gx[t] + Gx[t + 1024] + Gx[t + 2048] + Gx[t + 3072];
    __syncthreads();
    for (int m = 512; m >= 1; m >>= 1) {
        if (t < m) sm[t] += sm[t + m];
        __syncthreads();
    }
    if (t == 0) gsum[0] = sm[0];
}

__global__ __launch_bounds__(256) void k_topkf(const float* __restrict__ logits,
                                               const float* __restrict__ Gx,
                                               const float* __restrict__ gsum,
                                               const float* __restrict__ gamma,
                                               const float* __restrict__ beta,
                                               int* __restrict__ tidx, float* __restrict__ tp,
                                               int* __restrict__ counts,
                                               const float* __restrict__ W2,
                                               unsigned short* __restrict__ w2b) {
    if (blockIdx.x >= 16) {
        cvt_span(W2 + (SA + SB), w2b + (SA + SB), SC, blockIdx.x - 16, 1024);
        return;
    }
    int b = blockIdx.x * 256 + threadIdx.x;
    float nx = Gx[b] / (gsum[0] * (1.0f / (float)B_SZ) + GEPS);
    float l[NE];
    float mx = -1e30f;
#pragma unroll
    for (int e = 0; e < NE; ++e) {
        l[e] = gamma[e] * (logits[b * NE + e] * nx) + beta[e];
        mx = fmaxf(mx, l[e]);
    }
    float se = 0.f;
#pragma unroll
    for (int e = 0; e < NE; ++e) { l[e] = expf(l[e] - mx); se += l[e]; }
    float inv = 1.f / se;
    int i0 = 0; float p0 = l[0];
#pragma unroll
    for (int e = 1; e < NE; ++e) if (l[e] > p0) { p0 = l[e]; i0 = e; }
    int i1 = -1; float p1 = -1.f;
#pragma unroll
    for (int e = 0; e < NE; ++e) if (e != i0 && l[e] > p1) { p1 = l[e]; i1 = e; }
    tidx[b * 2 + 0] = i0; tidx[b * 2 + 1] = i1;
    tp[b * 2 + 0] = p0 * inv; tp[b * 2 + 1] = p1 * inv;
    atomicAdd(&counts[i0], 1);
    atomicAdd(&counts[i1], 1);
}

__global__ __launch_bounds__(256) void k_offsetsf(const int* __restrict__ counts,
                                                  int* __restrict__ offs,
                                                  const float* __restrict__ W2,
                                                  unsigned short* __restrict__ w2b) {
    if (blockIdx.x > 0) {
        cvt_span(W2 + (SA + SB + SC), w2b + (SA + SB + SC), SD, blockIdx.x - 1, 511);
        return;
    }
    if (threadIdx.x == 0) {
        int a = 0;
        for (int e = 0; e < NE; ++e) { offs[e] = a; a += counts[e]; }
    }
}

__global__ __launch_bounds__(256) void k_fillf(const int* __restrict__ tidx, const float* __restrict__ tp,
                                               const int* __restrict__ offs, int* __restrict__ cursors,
                                               int* __restrict__ rowsw, int* __restrict__ slotof,
                                               const float* __restrict__ W2,
                                               unsigned short* __restrict__ w2b) {
    if (blockIdx.x >= 16) {
        cvt_span(W2 + (SA + SB + SC + SD), w2b + (SA + SB + SC + SD), SE, blockIdx.x - 16, 1008);
        return;
    }
    int b = blockIdx.x * 256 + threadIdx.x;
#pragma unroll
    for (int k = 0; k < 2; ++k) {
        int e = tidx[b * 2 + k];
        int pos = atomicAdd(&cursors[e], 1);
        int at = offs[e] + pos;
        rowsw[at] = b * 2 + k;
        slotof[b * 2 + k] = at;
    }
}

// ====== 128x128 / BK=64, XOR-swizzled, double-buffered (round-6 proven) =========
// LDS buffer = [A 16KB | B 16KB]; buf0 @0, buf1 @32KB. LDS[r][slot] holds global
// chunk slot^(r&7); pre-swizzled source + swizzled ds_read (0 conflicts).
// 2 resident blocks/CU is the measured optimum (r8: 1 blk 14%; r17: 4 blk 28.5%).

__device__ __forceinline__ void compute_bk64(const short* buf, const int* aoff, const int* boff,
                                             floatx4 acc[4][4]) {
    const short* sA = buf;
    const short* sB = buf + 8192;
    short8 a0[4], a1[4], b0[4], b1[4];
#pragma unroll
    for (int i = 0; i < 4; ++i) {
        a0[i] = *(const short8*)(sA + aoff[i]);
        a1[i] = *(const short8*)(sA + (aoff[i] ^ 32));
        b0[i] = *(const short8*)(sB + boff[i]);
        b1[i] = *(const short8*)(sB + (boff[i] ^ 32));
    }
    asm volatile("s_waitcnt lgkmcnt(0)" ::: "memory");
    __builtin_amdgcn_sched_barrier(0);
    __builtin_amdgcn_s_setprio(1);
#pragma unroll
    for (int i = 0; i < 4; ++i)
#pragma unroll
        for (int j = 0; j < 4; ++j) {
            acc[i][j] = __builtin_amdgcn_mfma_f32_16x16x32_bf16(a0[i], b0[j], acc[i][j], 0, 0, 0);
            acc[i][j] = __builtin_amdgcn_mfma_f32_16x16x32_bf16(a1[i], b1[j], acc[i][j], 0, 0, 0);
        }
    __builtin_amdgcn_s_setprio(0);
}

__device__ __forceinline__ void stage_bk64(const unsigned short* const* pa,
                                           const unsigned short* const* pb,
                                           char* bufc, int koff, int tid) {
#pragma unroll
    for (int c = 0; c < 4; ++c) {
        async16(pa[c] + koff, bufc + c * 4096 + tid * 16);
        async16(pb[c] + koff, bufc + 16384 + c * 4096 + tid * 16);
    }
}

__device__ __forceinline__ void core64db(const unsigned short* const* pa,
                                         const unsigned short* const* pb,
                                         short* smem, int nkt, int wm, int wn,
                                         int tid, int lane, floatx4 acc[4][4]) {
    char* b0c = (char*)smem;
    char* b1c = b0c + 32768;
    const int sl = ((lane >> 4) ^ (lane & 7)) * 8;
    int aoff[4], boff[4];
#pragma unroll
    for (int i = 0; i < 4; ++i) {
        aoff[i] = (wm * 64 + i * 16 + (lane & 15)) * 64 + sl;
        boff[i] = (wn * 64 + i * 16 + (lane & 15)) * 64 + sl;
    }
    stage_bk64(pa, pb, b0c, 0, tid);
    __syncthreads();
#pragma unroll 1
    for (int kt = 0; kt < nkt; kt += 2) {
        if (kt + 1 < nkt) stage_bk64(pa, pb, b1c, (kt + 1) * 64, tid);
        compute_bk64(smem, aoff, boff, acc);
        __syncthreads();
        if (kt + 2 < nkt) stage_bk64(pa, pb, b0c, (kt + 2) * 64, tid);
        compute_bk64(smem + 16384, aoff, boff, acc);
        __syncthreads();
    }
}

// GEMM1: h = relu(x @ W1^T + b1)  — 128x128 tiles, grid 4096
__global__ __launch_bounds__(256) void k_h8(const unsigned short* __restrict__ xb,
                                            const unsigned short* __restrict__ w1b,
                                            const float* __restrict__ b1,
                                            unsigned short* __restrict__ hout) {
    extern __shared__ short smem[];
    const int tid = threadIdx.x, lane = tid & 63, wid = tid >> 6;
    const int wm = wid >> 1, wn = wid & 1;
    const int wg = (blockIdx.x & 7) * (gridDim.x >> 3) + (blockIdx.x >> 3);
    const int mt = wg & 31, nt = wg >> 5;
    const int m0 = mt * 128, n0 = nt * 128;
    const int srow = tid >> 3;
    const int cswz = ((tid & 7) ^ (srow & 7)) * 8;
    const unsigned short* pa[4];
    const unsigned short* pb[4];
#pragma unroll
    for (int c = 0; c < 4; ++c) {
        pa[c] = xb  + (size_t)(m0 + 32 * c + srow) * IN_SZ + cswz;
        pb[c] = w1b + (size_t)(n0 + 32 * c + srow) * IN_SZ + cswz;
    }
    floatx4 acc[4][4] = {};
    core64db(pa, pb, smem, IN_SZ / 64, wm, wn, tid, lane, acc);
#pragma unroll
    for (int i = 0; i < 4; ++i)
#pragma unroll
        for (int j = 0; j < 4; ++j)
#pragma unroll
            for (int r = 0; r < 4; ++r) {
                int row = m0 + wm * 64 + i * 16 + (lane >> 4) * 4 + r;
                int col = n0 + wn * 64 + j * 16 + (lane & 15);
                float v = acc[i][j][r] + b1[col];
                hout[(size_t)row * HIDE + col] = f2bf(fmaxf(v, 0.f));
            }
}

// GEMM2 grouped, split-K=2: gathered h rows x W2 expert slice -> bf16 partials
__global__ __launch_bounds__(256) void k_moe(const unsigned short* __restrict__ h,
                                             const unsigned short* __restrict__ w2b,
                                             const int* __restrict__ counts,
                                             const int* __restrict__ offs,
                                             const int* __restrict__ rowsw,
                                             unsigned short* __restrict__ parts) {
    // grid 4096 = 8e x 2sp x 8nt x 32mt; mt innermost -> same-XCD share B-panel
    const int wg = (blockIdx.x & 7) * (gridDim.x >> 3) + (blockIdx.x >> 3);
    const int mt = wg & 31, nt = (wg >> 5) & 7, sp = (wg >> 8) & 1, e = wg >> 9;
    const int gn = counts[e];
    if (mt * 128 >= gn) return;
    const int gbase = offs[e];
    extern __shared__ short smem[];
    const int tid = threadIdx.x, lane = tid & 63, wid = tid >> 6;
    const int wm = wid >> 1, wn = wid & 1;
    const int srow = tid >> 3;
    const int cswz = ((tid & 7) ^ (srow & 7)) * 8;
    const unsigned short* pa[4];
    const unsigned short* pb[4];
#pragma unroll
    for (int c = 0; c < 4; ++c) {
        int lr = mt * 128 + 32 * c + srow;
        if (lr > gn - 1) lr = gn - 1;
        int grow = rowsw[gbase + lr] >> 1;
        pa[c] = h + (size_t)grow * HIDE + sp * KSPL + cswz;
        pb[c] = w2b + (size_t)(e * OUTE + nt * 128 + 32 * c + srow) * HIDE + sp * KSPL + cswz;
    }
    floatx4 acc[4][4] = {};
    core64db(pa, pb, smem, KSPL / 64, wm, wn, tid, lane, acc);
    unsigned short* pbase = parts + (size_t)sp * B_SZ * 2 * OUTE;
#pragma unroll
    for (int i = 0; i < 4; ++i)
#pragma unroll
        for (int j = 0; j < 4; ++j)
#pragma unroll
            for (int r = 0; r < 4; ++r) {
                int lr = mt * 128 + wm * 64 + i * 16 + (lane >> 4) * 4 + r;
                if (lr < gn) {
                    int at = gbase + lr;
                    int col = nt * 128 + wn * 64 + j * 16 + (lane & 15);
                    pbase[(size_t)at * OUTE + col] = f2bf(acc[i][j][r]);
                }
            }
}

// reduce: ymix[b] = sum_k tp[b,k] * (sum_sp parts[sp][slot(b,k)] + b2[e_k])
__global__ __launch_bounds__(256) void k_reduce(const unsigned short* __restrict__ parts,
                                                const int* __restrict__ slotof,
                                                const int* __restrict__ tidx,
                                                const float* __restrict__ tp,
                                                const float* __restrict__ b2,
                                                unsigned short* __restrict__ ymix) {
    int i = blockIdx.x * 256 + threadIdx.x;
    int b = i >> 8, col = (i & 255) * 4;
    int at0 = slotof[b * 2], at1 = slotof[b * 2 + 1];
    int e0 = tidx[b * 2], e1 = tidx[b * 2 + 1];
    float q0 = tp[b * 2], q1 = tp[b * 2 + 1];
    float y0[4] = {0.f, 0.f, 0.f, 0.f}, y1[4] = {0.f, 0.f, 0.f, 0.f};
#pragma unroll
    for (int sp = 0; sp < NSPLIT; ++sp) {
        ushort4 u0 = *(const ushort4*)(parts + ((size_t)sp * B_SZ * 2 + at0) * OUTE + col);
        ushort4 u1 = *(const ushort4*)(parts + ((size_t)sp * B_SZ * 2 + at1) * OUTE + col);
        y0[0] += bf2f(u0.x); y0[1] += bf2f(u0.y); y0[2] += bf2f(u0.z); y0[3] += bf2f(u0.w);
        y1[0] += bf2f(u1.x); y1[1] += bf2f(u1.y); y1[2] += bf2f(u1.z); y1[3] += bf2f(u1.w);
    }
    float4 bb0 = *(const float4*)(b2 + (size_t)e0 * OUTE + col);
    float4 bb1 = *(const float4*)(b2 + (size_t)e1 * OUTE + col);
    ushort4 o;
    o.x = f2bf(q0 * (y0[0] + bb0.x) + q1 * (y1[0] + bb1.x));
    o.y = f2bf(q0 * (y0[1] + bb0.y) + q1 * (y1[1] + bb1.y));
    o.z = f2bf(q0 * (y0[2] + bb0.z) + q1 * (y1[2] + bb1.z));
    o.w = f2bf(q0 * (y0[3] + bb0.w) + q1 * (y1[3] + bb1.w));
    *(ushort4*)(ymix + (size_t)b * OUTE + col) = o;
}

// GEMM3: out = ymix @ Wc^T + bc  (r6 core, B rows clamped to NC)
__global__ __launch_bounds__(256) void k_gemm_out(const unsigned short* __restrict__ ymix,
                                                  const unsigned short* __restrict__ wcb,
                                                  const float* __restrict__ bc,
                                                  float* __restrict__ out) {
    const int mt = blockIdx.x >> 3, nt = blockIdx.x & 7;
    const int m0 = mt * 128, n0 = nt * 128;
    extern __shared__ short smem[];
    const int tid = threadIdx.x, lane = tid & 63, wid = tid >> 6;
    const int wm = wid >> 1, wn = wid & 1;
    const int srow = tid >> 3;
    const int cswz = ((tid & 7) ^ (srow & 7)) * 8;
    const unsigned short* pa[4];
    const unsigned short* pb[4];
#pragma unroll
    for (int c = 0; c < 4; ++c) {
        pa[c] = ymix + (size_t)(m0 + 32 * c + srow) * IN_SZ + cswz;
        int br = n0 + 32 * c + srow; if (br > NC - 1) br = NC - 1;
        pb[c] = wcb + (size_t)br * IN_SZ + cswz;
    }
    floatx4 acc[4][4] = {};
    core64db(pa, pb, smem, IN_SZ / 64, wm, wn, tid, lane, acc);
#pragma unroll
    for (int i = 0; i < 4; ++i)
#pragma unroll
        for (int j = 0; j < 4; ++j)
#pragma unroll
            for (int r = 0; r < 4; ++r) {
                int row = m0 + wm * 64 + i * 16 + (lane >> 4) * 4 + r;
                int col = n0 + wn * 64 + j * 16 + (lane & 15);
                if (col < NC)
                    out[(size_t)row * NC + col] = acc[i][j][r] + bc[col];
            }
}

extern "C" void kernel_launch(void* const* d_in, const int* in_sizes, int n_in,
                              void* d_out, int out_size, void* d_ws, size_t ws_size,
                              hipStream_t stream) {
    const float* x     = (const float*)d_in[0];
    const float* Wg    = (const float*)d_in[1];
    const float* bg    = (const float*)d_in[2];
    const float* gamma = (const float*)d_in[3];
    const float* beta  = (const float*)d_in[4];
    const float* W1    = (const float*)d_in[5];
    const float* b1    = (const float*)d_in[6];
    const float* W2    = (const float*)d_in[7];
    const float* b2    = (const float*)d_in[8];
    const float* Wc    = (const float*)d_in[9];
    const float* bc    = (const float*)d_in[10];
    float* out = (float*)d_out;

    char* ws = (char*)d_ws;
    size_t o = 0;
    auto carve = [&](size_t bytes) { char* p = ws + o; o += (bytes + 255) & ~(size_t)255; return p; };
    unsigned short* xb    = (unsigned short*)carve((size_t)B_SZ * IN_SZ * 2);
    unsigned short* w1b   = (unsigned short*)carve((size_t)HIDE * IN_SZ * 2);
    unsigned short* w2b   = (unsigned short*)carve((size_t)NE * OUTE * HIDE * 2);
    unsigned short* wcb   = (unsigned short*)carve((size_t)NC * IN_SZ * 2);
    unsigned short* h     = (unsigned short*)carve((size_t)B_SZ * HIDE * 2);
    unsigned short* parts = (unsigned short*)carve((size_t)NSPLIT * B_SZ * 2 * OUTE * 2);
    unsigned short* ymix  = (unsigned short*)carve((size_t)B_SZ * OUTE * 2);
    float* logits = (float*)carve((size_t)B_SZ * NE * 4);
    float* Gx     = (float*)carve((size_t)B_SZ * 4);
    int*   tidx   = (int*)carve((size_t)B_SZ * 2 * 4);
    float* tp     = (float*)carve((size_t)B_SZ * 2 * 4);
    int*   rowsw  = (int*)carve((size_t)B_SZ * 2 * 4);
    int*   slotof = (int*)carve((size_t)B_SZ * 2 * 4);
    int*   ctrl   = (int*)carve(256);
    int* counts  = ctrl;
    int* cursors = ctrl + 8;
    int* offs    = ctrl + 16;
    float* gsum  = (float*)(ctrl + 24);

    // 64KB dynamic LDS for the dbuf GEMM kernels (idempotent, not captured)
    hipFuncSetAttribute((const void*)k_h8,       hipFuncAttributeMaxDynamicSharedMemorySize, 65536);
    hipFuncSetAttribute((const void*)k_moe,      hipFuncAttributeMaxDynamicSharedMemorySize, 65536);
    hipFuncSetAttribute((const void*)k_gemm_out, hipFuncAttributeMaxDynamicSharedMemorySize, 65536);

    // gating chain carrying disjoint W2-conversion slices
    k_gatef<<<2624, 256, 0, stream>>>(x, Wg, bg, logits, Gx, xb, W1, w1b, Wc, wcb, W2, w2b);
    k_gsumf<<<2048, 1024, 0, stream>>>(Gx, gsum, ctrl, W2, w2b);
    k_topkf<<<1040, 256, 0, stream>>>(logits, Gx, gsum, gamma, beta, tidx, tp, counts, W2, w2b);
    k_offsetsf<<<512, 256, 0, stream>>>(counts, offs, W2, w2b);
    k_fillf<<<1024, 256, 0, stream>>>(tidx, tp, offs, cursors, rowsw, slotof, W2, w2b);

    // pure GEMMs (r13/r16 configuration: moe split-K=2, grid 4096)
    k_h8<<<(B_SZ / 128) * (HIDE / 128), 256, 65536, stream>>>(xb, w1b, b1, h);
    k_moe<<<NE * 32 * 8 * NSPLIT, 256, 65536, stream>>>(h, w2b, counts, offs, rowsw, parts);
    k_reduce<<<B_SZ, 256, 0, stream>>>(parts, slotof, tidx, tp, b2, ymix);
    k_gemm_out<<<(B_SZ / 128) * 8, 256, 65536, stream>>>(ymix, wcb, bc, out);
}